// Round 1
// baseline (291.851 us; speedup 1.0000x reference)
//
#include <hip/hip_runtime.h>
#include <math.h>

#define EPSF 1e-5f

typedef __attribute__((ext_vector_type(8))) __bf16 bf16x8;
typedef __attribute__((ext_vector_type(4))) float f32x4;

__device__ __forceinline__ unsigned short f2bf(float f) {
  unsigned int u = __float_as_uint(f);
  u += 0x7FFFu + ((u >> 16) & 1u);
  return (unsigned short)(u >> 16);
}

// ---- transpose + fp32->bf16: dst[c][r] = bf16(src[r][c]); src is R x C ----
__global__ __launch_bounds__(256) void k_transpose_bf16(
    const float* __restrict__ src, unsigned short* __restrict__ dst, int R, int C) {
  __shared__ float tile[32][33];
  int c0 = blockIdx.x * 32, r0 = blockIdx.y * 32;
  int x = threadIdx.x, y = threadIdx.y;  // block (32,8)
  #pragma unroll
  for (int yy = y; yy < 32; yy += 8)
    tile[yy][x] = src[(size_t)(r0 + yy) * C + (c0 + x)];
  __syncthreads();
  #pragma unroll
  for (int yy = y; yy < 32; yy += 8)
    dst[(size_t)(c0 + yy) * R + (r0 + x)] = f2bf(tile[x][yy]);
}

// ---- LN over 1024 elems per (b,s) + dt head -> xn (fp32), log_a ----
__global__ __launch_bounds__(256) void k_ln_dt(
    const float* __restrict__ x, const float* __restrict__ g, const float* __restrict__ bta,
    const float* __restrict__ w_dt, const float* __restrict__ b_dt,
    const float* __restrict__ log_A,
    float* __restrict__ xn, float* __restrict__ log_a) {
  int bs = blockIdx.x;
  int t = threadIdx.x;
  const float4* xr = (const float4*)(x + (size_t)bs * 1024);
  float4 v = xr[t];
  float s = v.x + v.y + v.z + v.w;
  float ss = v.x * v.x + v.y * v.y + v.z * v.z + v.w * v.w;
  #pragma unroll
  for (int o = 1; o < 64; o <<= 1) { s += __shfl_xor(s, o); ss += __shfl_xor(ss, o); }
  __shared__ float red[8];
  int w = t >> 6;
  if ((t & 63) == 0) { red[w] = s; red[4 + w] = ss; }
  __syncthreads();
  float S = red[0] + red[1] + red[2] + red[3];
  float SS = red[4] + red[5] + red[6] + red[7];
  float m = S * (1.0f / 1024.0f);
  float var = SS * (1.0f / 1024.0f) - m * m;
  float inv = rsqrtf(var + EPSF);
  float4 gv = ((const float4*)g)[t];
  float4 bv = ((const float4*)bta)[t];
  float4 o;
  o.x = (v.x - m) * inv * gv.x + bv.x;
  o.y = (v.y - m) * inv * gv.y + bv.y;
  o.z = (v.z - m) * inv * gv.z + bv.z;
  o.w = (v.w - m) * inv * gv.w + bv.w;
  ((float4*)(xn + (size_t)bs * 1024))[t] = o;
  // dt: rows of 32; thread t covers elems 4t..4t+3, all in row r = t>>3
  float4 wv = ((const float4*)w_dt)[t & 7];
  float part = o.x * wv.x + o.y * wv.y + o.z * wv.z + o.w * wv.w;
  part += __shfl_xor(part, 1);
  part += __shfl_xor(part, 2);
  part += __shfl_xor(part, 4);
  if ((t & 7) == 0) {
    int r = t >> 3;
    float z = part + b_dt[0];
    float sp = (z > 20.0f) ? z : log1pf(expf(z));      // softplus
    log_a[(size_t)bs * 32 + r] = sp * (-expf(log_A[r]));
  }
}

// ---- chunked scan: S_t = exp(log_a[t,r])*S_{t-1} + xn[t]; ssm = S_t + x ----
__global__ __launch_bounds__(256) void k_scan(
    const float* __restrict__ xn, const float* __restrict__ x,
    const float* __restrict__ log_a, float* __restrict__ ssm) {
  int b = blockIdx.x >> 5;
  int r = blockIdx.x & 31;
  __shared__ float decay[1024];
  __shared__ float sEnd[8][32];
  __shared__ float pArr[8];
  int tid = threadIdx.x;
  for (int t = tid; t < 1024; t += 256)
    decay[t] = expf(log_a[((size_t)b * 1024 + t) * 32 + r]);
  __syncthreads();
  int g = tid >> 5, c = tid & 31;
  size_t base = (size_t)b * 1024 * 1024 + (size_t)r * 32 + c;  // + t*1024
  int t0 = g * 128;
  float S = 0.0f, P = 1.0f;
  #pragma unroll 8
  for (int i = 0; i < 128; ++i) {
    float d = decay[t0 + i];
    S = d * S + xn[base + (size_t)(t0 + i) * 1024];
    P *= d;
  }
  sEnd[g][c] = S;
  if (c == 0) pArr[g] = P;
  __syncthreads();
  float Sin = 0.0f;
  for (int h = 0; h < g; ++h) Sin = pArr[h] * Sin + sEnd[h][c];
  S = Sin;
  #pragma unroll 8
  for (int i = 0; i < 128; ++i) {
    size_t idx = base + (size_t)(t0 + i) * 1024;
    float d = decay[t0 + i];
    S = d * S + xn[idx];
    ssm[idx] = S + x[idx];
  }
}

// ---- LN2 -> fn bf16 ----
__global__ __launch_bounds__(256) void k_ln2(
    const float* __restrict__ ssm, const float* __restrict__ g, const float* __restrict__ bta,
    unsigned short* __restrict__ fn) {
  int bs = blockIdx.x;
  int t = threadIdx.x;
  float4 v = ((const float4*)(ssm + (size_t)bs * 1024))[t];
  float s = v.x + v.y + v.z + v.w;
  float ss = v.x * v.x + v.y * v.y + v.z * v.z + v.w * v.w;
  #pragma unroll
  for (int o = 1; o < 64; o <<= 1) { s += __shfl_xor(s, o); ss += __shfl_xor(ss, o); }
  __shared__ float red[8];
  int w = t >> 6;
  if ((t & 63) == 0) { red[w] = s; red[4 + w] = ss; }
  __syncthreads();
  float S = red[0] + red[1] + red[2] + red[3];
  float SS = red[4] + red[5] + red[6] + red[7];
  float m = S * (1.0f / 1024.0f);
  float var = SS * (1.0f / 1024.0f) - m * m;
  float inv = rsqrtf(var + EPSF);
  float4 gv = ((const float4*)g)[t];
  float4 bv = ((const float4*)bta)[t];
  ushort4 o;
  o.x = f2bf((v.x - m) * inv * gv.x + bv.x);
  o.y = f2bf((v.y - m) * inv * gv.y + bv.y);
  o.z = f2bf((v.z - m) * inv * gv.z + bv.z);
  o.w = f2bf((v.w - m) * inv * gv.w + bv.w);
  ((ushort4*)(fn + (size_t)bs * 1024))[t] = o;
}

// ---- bf16 MFMA GEMM: C[M][N] = A[M][K] @ Bt[N][K]^T, epilogue variants ----
// EPI 0: Cout(bf16) = gelu(acc + bias[n]);  EPI 1: Cout(fp32) = acc + bias[n] + res[m][n]
template <int BN, int EPI>
__global__ __launch_bounds__(256) void k_gemm(
    const unsigned short* __restrict__ A, const unsigned short* __restrict__ Bt,
    const float* __restrict__ bias, const float* __restrict__ res,
    void* __restrict__ Cout, int M, int N, int K) {
  constexpr int BM = 128, BK = 32, LDT = 48;   // 48 bf16 = 96B row stride (16B-aligned)
  constexpr int WNT = BN / 32;                 // 16-wide n-tiles per wave
  __shared__ __align__(16) unsigned short sA[BM * LDT];
  __shared__ __align__(16) unsigned short sB[BN * LDT];
  int tid = threadIdx.x;
  int m0 = blockIdx.y * BM, n0 = blockIdx.x * BN;
  int wave = tid >> 6, lane = tid & 63;
  int wr = wave >> 1, wc = wave & 1;
  int l15 = lane & 15, quad = lane >> 4;

  f32x4 zero = {0.0f, 0.0f, 0.0f, 0.0f};
  f32x4 acc[4][WNT];
  #pragma unroll
  for (int i = 0; i < 4; ++i)
    #pragma unroll
    for (int j = 0; j < WNT; ++j) acc[i][j] = zero;

  constexpr int ACH = BM * BK / 8;  // 16B chunks
  constexpr int BCH = BN * BK / 8;

  for (int k0 = 0; k0 < K; k0 += BK) {
    #pragma unroll
    for (int q = tid; q < ACH; q += 256) {
      int row = q >> 2, cq = q & 3;
      *(uint4*)(&sA[row * LDT + cq * 8]) =
          *(const uint4*)(A + (size_t)(m0 + row) * K + k0 + cq * 8);
    }
    #pragma unroll
    for (int q = tid; q < BCH; q += 256) {
      int row = q >> 2, cq = q & 3;
      *(uint4*)(&sB[row * LDT + cq * 8]) =
          *(const uint4*)(Bt + (size_t)(n0 + row) * K + k0 + cq * 8);
    }
    __syncthreads();
    bf16x8 af[4], bfr[WNT];
    #pragma unroll
    for (int i = 0; i < 4; ++i)
      af[i] = *(const bf16x8*)(&sA[(wr * 64 + i * 16 + l15) * LDT + quad * 8]);
    #pragma unroll
    for (int j = 0; j < WNT; ++j)
      bfr[j] = *(const bf16x8*)(&sB[(wc * (WNT * 16) + j * 16 + l15) * LDT + quad * 8]);
    #pragma unroll
    for (int i = 0; i < 4; ++i)
      #pragma unroll
      for (int j = 0; j < WNT; ++j)
        acc[i][j] = __builtin_amdgcn_mfma_f32_16x16x32_bf16(af[i], bfr[j], acc[i][j], 0, 0, 0);
    __syncthreads();
  }

  #pragma unroll
  for (int i = 0; i < 4; ++i)
    #pragma unroll
    for (int j = 0; j < WNT; ++j) {
      int col = n0 + wc * (WNT * 16) + j * 16 + l15;
      float bval = bias[col];
      #pragma unroll
      for (int v = 0; v < 4; ++v) {
        int row = m0 + wr * 64 + i * 16 + quad * 4 + v;
        float val = acc[i][j][v] + bval;
        if (EPI == 0) {
          val = 0.5f * val * (1.0f + erff(val * 0.70710678118654752f));
          ((unsigned short*)Cout)[(size_t)row * N + col] = f2bf(val);
        } else {
          ((float*)Cout)[(size_t)row * N + col] = val + res[(size_t)row * N + col];
        }
      }
    }
}

extern "C" void kernel_launch(void* const* d_in, const int* in_sizes, int n_in,
                              void* d_out, int out_size, void* d_ws, size_t ws_size,
                              hipStream_t stream) {
  const float* x     = (const float*)d_in[0];
  const float* log_A = (const float*)d_in[1];
  const float* w_dt  = (const float*)d_in[2];
  const float* b_dt  = (const float*)d_in[3];
  const float* g_ssm = (const float*)d_in[4];
  const float* b_ssm = (const float*)d_in[5];
  const float* g_ffn = (const float*)d_in[6];
  const float* b_ffn = (const float*)d_in[7];
  const float* W1    = (const float*)d_in[8];
  const float* bb1   = (const float*)d_in[9];
  const float* W2    = (const float*)d_in[10];
  const float* bb2   = (const float*)d_in[11];
  float* out = (float*)d_out;

  char* ws = (char*)d_ws;
  size_t off = 0;
  float* xn   = (float*)(ws + off); off += (size_t)8 << 20;
  float* ssm  = (float*)(ws + off); off += (size_t)8 << 20;
  float* loga = (float*)(ws + off); off += (size_t)1 << 20;
  unsigned short* fn  = (unsigned short*)(ws + off); off += (size_t)4 << 20;
  unsigned short* W1t = (unsigned short*)(ws + off); off += (size_t)8 << 20;
  unsigned short* W2t = (unsigned short*)(ws + off); off += (size_t)8 << 20;
  unsigned short* hbf = (unsigned short*)(ws + off); off += (size_t)16 << 20;

  // weight convert + transpose to [N][K] bf16
  k_transpose_bf16<<<dim3(4096 / 32, 1024 / 32), dim3(32, 8), 0, stream>>>(W1, W1t, 1024, 4096);
  k_transpose_bf16<<<dim3(1024 / 32, 4096 / 32), dim3(32, 8), 0, stream>>>(W2, W2t, 4096, 1024);
  // LN1 + dt
  k_ln_dt<<<2048, 256, 0, stream>>>(x, g_ssm, b_ssm, w_dt, b_dt, log_A, xn, loga);
  // SSM chunked scan (+ residual)
  k_scan<<<64, 256, 0, stream>>>(xn, x, loga, ssm);
  // LN2 -> bf16
  k_ln2<<<2048, 256, 0, stream>>>(ssm, g_ffn, b_ffn, fn);
  // FFN GEMMs
  k_gemm<128, 0><<<dim3(4096 / 128, 2048 / 128), 256, 0, stream>>>(
      fn, W1t, bb1, nullptr, (void*)hbf, 2048, 4096, 1024);
  k_gemm<64, 1><<<dim3(1024 / 64, 2048 / 128), 256, 0, stream>>>(
      hbf, W2t, bb2, ssm, (void*)out, 2048, 1024, 4096);
}

// Round 2
// 205.071 us; speedup vs baseline: 1.4232x; 1.4232x over previous
//
#include <hip/hip_runtime.h>
#include <math.h>

#define EPSF 1e-5f

typedef __attribute__((ext_vector_type(8))) __bf16 bf16x8;
typedef __attribute__((ext_vector_type(4))) float f32x4;

__device__ __forceinline__ unsigned short f2bf(float f) {
  unsigned int u = __float_as_uint(f);
  u += 0x7FFFu + ((u >> 16) & 1u);
  return (unsigned short)(u >> 16);
}

__device__ __forceinline__ void async_load16(const void* g, void* l) {
  __builtin_amdgcn_global_load_lds(
      (const __attribute__((address_space(1))) void*)g,
      (__attribute__((address_space(3))) void*)l, 16, 0, 0);
}

// ---- transpose + fp32->bf16: dst[c][r] = bf16(src[r][c]); src is R x C ----
__global__ __launch_bounds__(256) void k_transpose_bf16(
    const float* __restrict__ src, unsigned short* __restrict__ dst, int R, int C) {
  __shared__ float tile[32][33];
  int c0 = blockIdx.x * 32, r0 = blockIdx.y * 32;
  int x = threadIdx.x, y = threadIdx.y;  // block (32,8)
  #pragma unroll
  for (int yy = y; yy < 32; yy += 8)
    tile[yy][x] = src[(size_t)(r0 + yy) * C + (c0 + x)];
  __syncthreads();
  #pragma unroll
  for (int yy = y; yy < 32; yy += 8)
    dst[(size_t)(c0 + yy) * R + (r0 + x)] = f2bf(tile[x][yy]);
}

// ---- LN over 1024 elems per (b,s) + dt head -> xn (fp32), log_a ----
__global__ __launch_bounds__(256) void k_ln_dt(
    const float* __restrict__ x, const float* __restrict__ g, const float* __restrict__ bta,
    const float* __restrict__ w_dt, const float* __restrict__ b_dt,
    const float* __restrict__ log_A,
    float* __restrict__ xn, float* __restrict__ log_a) {
  int bs = blockIdx.x;
  int t = threadIdx.x;
  const float4* xr = (const float4*)(x + (size_t)bs * 1024);
  float4 v = xr[t];
  float s = v.x + v.y + v.z + v.w;
  float ss = v.x * v.x + v.y * v.y + v.z * v.z + v.w * v.w;
  #pragma unroll
  for (int o = 1; o < 64; o <<= 1) { s += __shfl_xor(s, o); ss += __shfl_xor(ss, o); }
  __shared__ float red[8];
  int w = t >> 6;
  if ((t & 63) == 0) { red[w] = s; red[4 + w] = ss; }
  __syncthreads();
  float S = red[0] + red[1] + red[2] + red[3];
  float SS = red[4] + red[5] + red[6] + red[7];
  float m = S * (1.0f / 1024.0f);
  float var = SS * (1.0f / 1024.0f) - m * m;
  float inv = rsqrtf(var + EPSF);
  float4 gv = ((const float4*)g)[t];
  float4 bv = ((const float4*)bta)[t];
  float4 o;
  o.x = (v.x - m) * inv * gv.x + bv.x;
  o.y = (v.y - m) * inv * gv.y + bv.y;
  o.z = (v.z - m) * inv * gv.z + bv.z;
  o.w = (v.w - m) * inv * gv.w + bv.w;
  ((float4*)(xn + (size_t)bs * 1024))[t] = o;
  // dt: rows of 32; thread t covers elems 4t..4t+3, all in row r = t>>3
  float4 wv = ((const float4*)w_dt)[t & 7];
  float part = o.x * wv.x + o.y * wv.y + o.z * wv.z + o.w * wv.w;
  part += __shfl_xor(part, 1);
  part += __shfl_xor(part, 2);
  part += __shfl_xor(part, 4);
  if ((t & 7) == 0) {
    int r = t >> 3;
    float z = part + b_dt[0];
    float sp = (z > 20.0f) ? z : log1pf(expf(z));      // softplus
    log_a[(size_t)bs * 32 + r] = sp * (-expf(log_A[r]));
  }
}

// ---- chunked scan, 2 passes. chains (b,r,c); S_t = d_t*S_{t-1} + xn_t ----
// grid 512: (b, r, ch) with 8 chunks of 128 steps; 256 thr = 8 subs x 32 c.
// PASS 0: write per-chunk end-state E[b][r][ch][c] and decay product P.
// PASS 1: combine prior chunks -> init, full scan, ssm = S + x.
template <int PASS>
__global__ __launch_bounds__(256) void k_scan_pass(
    const float* __restrict__ xn, const float* __restrict__ x,
    const float* __restrict__ loga, float* __restrict__ E, float* __restrict__ P,
    float* __restrict__ ssm) {
  int bx = blockIdx.x;
  int b = bx >> 8, r = (bx >> 3) & 31, ch = bx & 7;
  int tid = threadIdx.x, c = tid & 31, sub = tid >> 5;
  __shared__ float dec[128];
  __shared__ float sE[8][32];
  __shared__ float sP[8];
  if (tid < 128)
    dec[tid] = expf(loga[((size_t)(b * 1024 + ch * 128 + tid)) * 32 + r]);
  __syncthreads();
  int t0 = ch * 128 + sub * 16;
  size_t base = ((size_t)(b * 1024 + t0)) * 1024 + r * 32 + c;
  float xv[16];
  #pragma unroll
  for (int i = 0; i < 16; ++i) xv[i] = xn[base + (size_t)i * 1024];
  float S = 0.0f, Pl = 1.0f;
  #pragma unroll
  for (int i = 0; i < 16; ++i) { float d = dec[sub * 16 + i]; S = d * S + xv[i]; Pl *= d; }
  sE[sub][c] = S;
  if (c == 0) sP[sub] = Pl;
  __syncthreads();
  if (PASS == 0) {
    if (tid < 32) {
      float st = 0.0f, pp = 1.0f;
      #pragma unroll
      for (int h = 0; h < 8; ++h) { st = sP[h] * st + sE[h][tid]; pp *= sP[h]; }
      E[((size_t)(b * 32 + r) * 8 + ch) * 32 + tid] = st;
      if (tid == 0) P[(b * 32 + r) * 8 + ch] = pp;
    }
  } else {
    float Sin = 0.0f;
    const float* Eb = E + (size_t)(b * 32 + r) * 8 * 32 + c;
    const float* Pb = P + (size_t)(b * 32 + r) * 8;
    for (int h = 0; h < ch; ++h) Sin = Pb[h] * Sin + Eb[h * 32];
    for (int h = 0; h < sub; ++h) Sin = sP[h] * Sin + sE[h][c];
    float S2 = Sin;
    #pragma unroll
    for (int i = 0; i < 16; ++i) {
      float d = dec[sub * 16 + i];
      S2 = d * S2 + xv[i];
      size_t idx = base + (size_t)i * 1024;
      ssm[idx] = S2 + x[idx];
    }
  }
}

// ---- LN2 -> fn bf16 ----
__global__ __launch_bounds__(256) void k_ln2(
    const float* __restrict__ ssm, const float* __restrict__ g, const float* __restrict__ bta,
    unsigned short* __restrict__ fn) {
  int bs = blockIdx.x;
  int t = threadIdx.x;
  float4 v = ((const float4*)(ssm + (size_t)bs * 1024))[t];
  float s = v.x + v.y + v.z + v.w;
  float ss = v.x * v.x + v.y * v.y + v.z * v.z + v.w * v.w;
  #pragma unroll
  for (int o = 1; o < 64; o <<= 1) { s += __shfl_xor(s, o); ss += __shfl_xor(ss, o); }
  __shared__ float red[8];
  int w = t >> 6;
  if ((t & 63) == 0) { red[w] = s; red[4 + w] = ss; }
  __syncthreads();
  float S = red[0] + red[1] + red[2] + red[3];
  float SS = red[4] + red[5] + red[6] + red[7];
  float m = S * (1.0f / 1024.0f);
  float var = SS * (1.0f / 1024.0f) - m * m;
  float inv = rsqrtf(var + EPSF);
  float4 gv = ((const float4*)g)[t];
  float4 bv = ((const float4*)bta)[t];
  ushort4 o;
  o.x = f2bf((v.x - m) * inv * gv.x + bv.x);
  o.y = f2bf((v.y - m) * inv * gv.y + bv.y);
  o.z = f2bf((v.z - m) * inv * gv.z + bv.z);
  o.w = f2bf((v.w - m) * inv * gv.w + bv.w);
  ((ushort4*)(fn + (size_t)bs * 1024))[t] = o;
}

// ---- m97-style bf16 MFMA GEMM: 128x128 block, 4 waves of 64x64, BK=32,
// async global_load_lds (16B), unpadded 64B LDS row stride (conflict-free).
// EPI 0: C0(bf16) = gelu(acc + bias[n]), kLen = K.
// EPI 1: split-K partials fp32, ks = blockIdx.z, dst = (ks<2?C0:C1)+(ks&1)*M*N.
template <int EPI>
__global__ __launch_bounds__(256) void k_gemm_m97(
    const unsigned short* __restrict__ A, const unsigned short* __restrict__ Bt,
    const float* __restrict__ bias, void* __restrict__ C0, void* __restrict__ C1,
    int M, int N, int K, int kLen) {
  __shared__ __align__(16) unsigned short sA[128 * 32];
  __shared__ __align__(16) unsigned short sB[128 * 32];
  int tid = threadIdx.x;
  int m0 = blockIdx.y * 128, n0 = blockIdx.x * 128;
  int ks = (EPI == 1) ? blockIdx.z : 0;
  int kOff = ks * kLen;
  int wave = tid >> 6, lane = tid & 63;
  int wr = wave >> 1, wc = wave & 1;
  int l15 = lane & 15, quad = lane >> 4;

  // staging chunks (16B each): c = row*4 + kq, LDS offset c*16B
  int c0 = tid, c1 = tid + 256;
  const unsigned short* gA0 = A + (size_t)(m0 + (c0 >> 2)) * K + kOff + (c0 & 3) * 8;
  const unsigned short* gA1 = A + (size_t)(m0 + (c1 >> 2)) * K + kOff + (c1 & 3) * 8;
  const unsigned short* gB0 = Bt + (size_t)(n0 + (c0 >> 2)) * K + kOff + (c0 & 3) * 8;
  const unsigned short* gB1 = Bt + (size_t)(n0 + (c1 >> 2)) * K + kOff + (c1 & 3) * 8;
  unsigned short* lA0 = sA + (size_t)(c0 & ~63) * 8;
  unsigned short* lA1 = sA + (size_t)((c1 - lane)) * 8;
  unsigned short* lB0 = sB + (size_t)(c0 & ~63) * 8;
  unsigned short* lB1 = sB + (size_t)((c1 - lane)) * 8;

  f32x4 zero = {0.0f, 0.0f, 0.0f, 0.0f};
  f32x4 acc[4][4];
  #pragma unroll
  for (int i = 0; i < 4; ++i)
    #pragma unroll
    for (int j = 0; j < 4; ++j) acc[i][j] = zero;

  const unsigned short* pa = sA + (wr * 64 + l15) * 32 + quad * 8;
  const unsigned short* pb = sB + (wc * 64 + l15) * 32 + quad * 8;

  for (int k0 = 0; k0 < kLen; k0 += 32) {
    async_load16(gA0, lA0);
    async_load16(gA1, lA1);
    async_load16(gB0, lB0);
    async_load16(gB1, lB1);
    gA0 += 32; gA1 += 32; gB0 += 32; gB1 += 32;
    __syncthreads();
    bf16x8 af[4], bfr[4];
    #pragma unroll
    for (int i = 0; i < 4; ++i) af[i] = *(const bf16x8*)(pa + i * 512);
    #pragma unroll
    for (int j = 0; j < 4; ++j) bfr[j] = *(const bf16x8*)(pb + j * 512);
    #pragma unroll
    for (int i = 0; i < 4; ++i)
      #pragma unroll
      for (int j = 0; j < 4; ++j)
        acc[i][j] = __builtin_amdgcn_mfma_f32_16x16x32_bf16(af[i], bfr[j], acc[i][j], 0, 0, 0);
    __syncthreads();
  }

  if (EPI == 0) {
    unsigned short* Cb = (unsigned short*)C0;
    #pragma unroll
    for (int i = 0; i < 4; ++i)
      #pragma unroll
      for (int j = 0; j < 4; ++j) {
        int col = n0 + wc * 64 + j * 16 + l15;
        float bval = bias[col];
        #pragma unroll
        for (int v = 0; v < 4; ++v) {
          int row = m0 + wr * 64 + i * 16 + quad * 4 + v;
          float val = acc[i][j][v] + bval;
          val = 0.5f * val * (1.0f + erff(val * 0.70710678118654752f));
          Cb[(size_t)row * N + col] = f2bf(val);
        }
      }
  } else {
    float* dst = ((ks < 2) ? (float*)C0 : (float*)C1) + (size_t)(ks & 1) * M * N;
    #pragma unroll
    for (int i = 0; i < 4; ++i)
      #pragma unroll
      for (int j = 0; j < 4; ++j) {
        int col = n0 + wc * 64 + j * 16 + l15;
        #pragma unroll
        for (int v = 0; v < 4; ++v) {
          int row = m0 + wr * 64 + i * 16 + quad * 4 + v;
          dst[(size_t)row * N + col] = acc[i][j][v];
        }
      }
  }
}

// ---- split-K reduce + bias + residual ----
__global__ __launch_bounds__(256) void k_reduce(
    const float* __restrict__ pA, const float* __restrict__ pB,
    const float* __restrict__ bias, const float* __restrict__ res,
    float* __restrict__ out, int KS) {
  int i = blockIdx.x * 256 + threadIdx.x;  // float4 index; MN/4 = 524288
  const int MN4 = 524288;
  float4 v = ((const float4*)pA)[i];
  float4 w = ((const float4*)pA)[i + MN4];
  v.x += w.x; v.y += w.y; v.z += w.z; v.w += w.w;
  if (KS == 4) {
    float4 u0 = ((const float4*)pB)[i];
    float4 u1 = ((const float4*)pB)[i + MN4];
    v.x += u0.x + u1.x; v.y += u0.y + u1.y; v.z += u0.z + u1.z; v.w += u0.w + u1.w;
  }
  float4 bb = ((const float4*)bias)[i & 255];
  float4 rr = ((const float4*)res)[i];
  float4 o;
  o.x = v.x + bb.x + rr.x; o.y = v.y + bb.y + rr.y;
  o.z = v.z + bb.z + rr.z; o.w = v.w + bb.w + rr.w;
  ((float4*)out)[i] = o;
}

extern "C" void kernel_launch(void* const* d_in, const int* in_sizes, int n_in,
                              void* d_out, int out_size, void* d_ws, size_t ws_size,
                              hipStream_t stream) {
  const float* x     = (const float*)d_in[0];
  const float* log_A = (const float*)d_in[1];
  const float* w_dt  = (const float*)d_in[2];
  const float* b_dt  = (const float*)d_in[3];
  const float* g_ssm = (const float*)d_in[4];
  const float* b_ssm = (const float*)d_in[5];
  const float* g_ffn = (const float*)d_in[6];
  const float* b_ffn = (const float*)d_in[7];
  const float* W1    = (const float*)d_in[8];
  const float* bb1   = (const float*)d_in[9];
  const float* W2    = (const float*)d_in[10];
  const float* bb2   = (const float*)d_in[11];
  float* out = (float*)d_out;

  const size_t MB = 1u << 20;
  char* ws = (char*)d_ws;
  float* xn            = (float*)(ws);                 // 8 MB   (dies after scan p1)
  unsigned short* W1t  = (unsigned short*)(ws + 8 * MB);   // 8 MB (dies after gemm1)
  float* loga          = (float*)(ws + 16 * MB);           // 256 KB
  float* Ebuf          = (float*)(ws + 17 * MB);           // 64 KB
  float* Pbuf          = (float*)(ws + 17 * MB + 131072);  // 2 KB
  unsigned short* fn   = (unsigned short*)(ws + 18 * MB);  // 4 MB
  float* ssm           = (float*)(ws + 22 * MB);           // 8 MB (live to end)
  unsigned short* W2t  = (unsigned short*)(ws + 30 * MB);  // 8 MB
  unsigned short* hbf  = (unsigned short*)(ws + 38 * MB);  // 16 MB -> end 54 MB
  float* pA = (float*)(ws);                                // 16 MB over xn+W1t
  float* pB;
  int KS;
  if (ws_size >= (size_t)71 * MB) { pB = (float*)(ws + 54 * MB); KS = 4; }
  else                            { pB = pA;                     KS = 2; }

  k_transpose_bf16<<<dim3(128, 32), dim3(32, 8), 0, stream>>>(W1, W1t, 1024, 4096);
  k_transpose_bf16<<<dim3(32, 128), dim3(32, 8), 0, stream>>>(W2, W2t, 4096, 1024);
  k_ln_dt<<<2048, 256, 0, stream>>>(x, g_ssm, b_ssm, w_dt, b_dt, log_A, xn, loga);
  k_scan_pass<0><<<512, 256, 0, stream>>>(xn, x, loga, Ebuf, Pbuf, ssm);
  k_scan_pass<1><<<512, 256, 0, stream>>>(xn, x, loga, Ebuf, Pbuf, ssm);
  k_ln2<<<2048, 256, 0, stream>>>(ssm, g_ffn, b_ffn, fn);
  k_gemm_m97<0><<<dim3(32, 16), 256, 0, stream>>>(
      fn, W1t, bb1, (void*)hbf, (void*)hbf, 2048, 4096, 1024, 1024);
  k_gemm_m97<1><<<dim3(8, 16, KS), 256, 0, stream>>>(
      hbf, W2t, nullptr, (void*)pA, (void*)pB, 2048, 1024, 4096, 4096 / KS);
  k_reduce<<<2048, 256, 0, stream>>>(pA, pB, bb2, ssm, out, KS);
}